// Round 2
// baseline (600.034 us; speedup 1.0000x reference)
//
#include <hip/hip_runtime.h>
#include <hip/hip_bf16.h>

// ClusteringLayer: q[n,k] = norm_k( 1 / (1 + ||x_n - c_k||^2) ), alpha=1 (power=1, no-op)
// N=131072, D=256, K=256, fp32 in/out. HBM-bound floor ~43us.
// R1 redesign: stage FULL clusters (256x256 bf16 = 128KB LDS, XOR-swizzled) once
// per block; barrier-free main loop (2 row-tiles/wave, 1-kchunk A-load lookahead)
// so waves progress heterogeneously and hide HBM latency. 1024 thr (16 waves),
// grid=256 (1 block/CU), launch_bounds(1024,4) to cap regs at 128/wave.

#define DDIM 256
#define KCL 256

typedef __bf16 v8bf __attribute__((ext_vector_type(8)));
typedef float f32x4 __attribute__((ext_vector_type(4)));

__global__ __launch_bounds__(1024, 4) void cluster_soft_assign(
    const float* __restrict__ X, const float* __restrict__ C,
    float* __restrict__ out, int iters)
{
    // Bs[col][d] bf16, swizzled d' = d ^ ((col&7)<<3) (flips bits 3-5, stays in
    // any 64-block) -> kills the stride-512B ds_read_b128 16-way bank conflict.
    __shared__ __align__(16) __bf16 Bs[KCL * DDIM];   // 128 KB
    __shared__ float red[1024];
    __shared__ float csq_s[KCL];

    const int t    = threadIdx.x;
    const int wave = t >> 6;
    const int lane = t & 63;
    const int lr   = lane & 15;   // A row / C col fragment index
    const int kg   = lane >> 4;   // k-group

    // ---- prologue: stage full C (fp32->bf16) once; exact fp32 c_sq ----------
    {
        const int col = t & 255;
        const int dq  = (t >> 8) * 64;          // 4 threads per col
        const int sw  = (col & 7) << 3;
        const float* cp = C + (size_t)col * DDIM + dq;
        float csq_part = 0.f;
#pragma unroll
        for (int g = 0; g < 8; ++g) {
            const float4 f0 = *(const float4*)(cp + g * 8);
            const float4 f1 = *(const float4*)(cp + g * 8 + 4);
            csq_part += f0.x*f0.x + f0.y*f0.y + f0.z*f0.z + f0.w*f0.w
                      + f1.x*f1.x + f1.y*f1.y + f1.z*f1.z + f1.w*f1.w;
            v8bf pk;
            pk[0]=(__bf16)f0.x; pk[1]=(__bf16)f0.y; pk[2]=(__bf16)f0.z; pk[3]=(__bf16)f0.w;
            pk[4]=(__bf16)f1.x; pk[5]=(__bf16)f1.y; pk[6]=(__bf16)f1.z; pk[7]=(__bf16)f1.w;
            const int d = dq + g * 8;
            *(v8bf*)&Bs[col * DDIM + (d ^ sw)] = pk;
        }
        red[t] = csq_part;
    }
    __syncthreads();
    if (t < 256) csq_s[t] = red[t] + red[t + 256] + red[t + 512] + red[t + 768];
    __syncthreads();
    // ---- no barriers from here on -------------------------------------------

    const int swl = (lr & 7) << 3;   // (col&7)<<3 with col = tl*16+lr

    for (int it = 0; it < iters; ++it) {
        const size_t rowbase = ((size_t)blockIdx.x * iters + it) * 256;
        const float* xrow = X + (rowbase + wave * 16 + lr) * DDIM + kg * 8;

        f32x4 acc[16];
#pragma unroll
        for (int i = 0; i < 16; ++i) { acc[i][0]=0.f; acc[i][1]=0.f; acc[i][2]=0.f; acc[i][3]=0.f; }
        float xsq = 0.f;

        // 1-kchunk lookahead on A loads (load-to-use spans 16 ds_read + 16 MFMA)
        float4 c0 = *(const float4*)(xrow + 0);
        float4 c1 = *(const float4*)(xrow + 4);
#pragma unroll
        for (int kc = 0; kc < 8; ++kc) {
            float4 n0, n1;
            if (kc < 7) {
                n0 = *(const float4*)(xrow + (kc + 1) * 32);
                n1 = *(const float4*)(xrow + (kc + 1) * 32 + 4);
            }
            xsq += c0.x*c0.x + c0.y*c0.y + c0.z*c0.z + c0.w*c0.w
                 + c1.x*c1.x + c1.y*c1.y + c1.z*c1.z + c1.w*c1.w;
            v8bf af;
            af[0]=(__bf16)c0.x; af[1]=(__bf16)c0.y; af[2]=(__bf16)c0.z; af[3]=(__bf16)c0.w;
            af[4]=(__bf16)c1.x; af[5]=(__bf16)c1.y; af[6]=(__bf16)c1.z; af[7]=(__bf16)c1.w;

            const int dbase = kc * 32 + kg * 8;
#pragma unroll
            for (int tl = 0; tl < 16; ++tl) {
                const int col = tl * 16 + lr;
                const v8bf bf = *(const v8bf*)&Bs[col * DDIM + (dbase ^ swl)];
                acc[tl] = __builtin_amdgcn_mfma_f32_16x16x32_bf16(af, bf, acc[tl], 0, 0, 0);
            }
            c0 = n0; c1 = n1;
        }

        // xsq: reduce over the 4 k-groups -> lane holds xsq(row = lane&15)
        xsq += __shfl_xor(xsq, 16);
        xsq += __shfl_xor(xsq, 32);

        // epilogue: C/D layout col = lane&15, row = kg*4 + j (m89-verified)
#pragma unroll
        for (int j = 0; j < 4; ++j) {
            const size_t orow = rowbase + wave * 16 + kg * 4 + j;
            const float xs = __shfl(xsq, kg * 4 + j);
            float qv[16];
            float s = 0.f;
#pragma unroll
            for (int tl = 0; tl < 16; ++tl) {
                const float cs = csq_s[tl * 16 + lr];
                float d2 = xs + cs - 2.f * acc[tl][j];
                d2 = fmaxf(d2, 0.f);
                const float q = 1.f / (1.f + d2);
                qv[tl] = q;
                s += q;
            }
            s += __shfl_xor(s, 1);
            s += __shfl_xor(s, 2);
            s += __shfl_xor(s, 4);
            s += __shfl_xor(s, 8);
            const float r = 1.f / s;
            float* op = out + orow * DDIM + lr;
#pragma unroll
            for (int tl = 0; tl < 16; ++tl) op[tl * 16] = qv[tl] * r;
        }
    }
}

extern "C" void kernel_launch(void* const* d_in, const int* in_sizes, int n_in,
                              void* d_out, int out_size, void* d_ws, size_t ws_size,
                              hipStream_t stream) {
    const float* X = (const float*)d_in[0];   // (N, 256) fp32
    const float* C = (const float*)d_in[1];   // (256, 256) fp32
    float* out = (float*)d_out;               // (N, 256) fp32
    const int N = in_sizes[0] / DDIM;
    int nblocks = N / 256;                    // row-tiles of 256
    if (nblocks > 256) nblocks = 256;         // 1 block per CU
    const int iters = N / (nblocks * 256);    // 131072 -> 256 blocks x 2 iters
    hipLaunchKernelGGL(cluster_soft_assign, dim3(nblocks), dim3(1024), 0, stream,
                       X, C, out, iters);
}

// Round 3
// 271.908 us; speedup vs baseline: 2.2068x; 2.2068x over previous
//
#include <hip/hip_runtime.h>
#include <hip/hip_bf16.h>

// ClusteringLayer: q[n,k] = norm_k( 1 / (1 + ||x_n - c_k||^2) ), alpha=1 (power=1 no-op)
// N=131072, D=256, K=256, fp32 in/out. Traffic floor ~268MB -> ~43us.
// R2 = R0 structure (123us, verified) + latency fixes:
//  - double-buffered C staging, async split: chunk c+1 global loads issued one
//    full MFMA phase before their ds_write -> barriers wait on LDS only
//  - full A-row prefetch in prologue, converted to bf16 frags early
//  - epilogue: rcp (not IEEE div), csq in regs, wave-private LDS transpose
//    (reusing buf0) -> global_store_dwordx4 full-row stores

#define DDIM 256
#define KCL 256
#define BM 128          // rows per block (8 waves x 16 rows)
#define DCHUNK 64

typedef __bf16 v8bf __attribute__((ext_vector_type(8)));
typedef float f32x4 __attribute__((ext_vector_type(4)));

__global__ __launch_bounds__(512, 2) void cluster_soft_assign(
    const float* __restrict__ X, const float* __restrict__ C,
    float* __restrict__ out)
{
    // Bs[b][col][d] bf16, 128B col-stride, swizzle d' = d ^ ((col&7)<<3)
    // (R0 layout: measured 0 bank conflicts)
    __shared__ __align__(16) __bf16 Bs[2][KCL * DCHUNK];   // 64 KB
    __shared__ float csq_s[KCL];

    const int t    = threadIdx.x;
    const int wave = t >> 6;
    const int lane = t & 63;
    const int lr   = lane & 15;   // A row / C col fragment index
    const int kg   = lane >> 4;   // k-group

    const size_t brow = (size_t)blockIdx.x * BM;
    const float* xrow = X + (brow + wave * 16 + lr) * DDIM + kg * 8;

    // staging map: thread -> (cluster col, 32-float half of the 64-d chunk)
    const int scol = t >> 1;
    const int sd0  = (t & 1) * 32;
    const float* cbase = C + (size_t)scol * DDIM + sd0;

    float4 sr[8];            // staged C-chunk (global->reg, written to LDS later)
    float  csq_part = 0.f;

    auto stage_load = [&](int c) {
        const float* cp = cbase + c * DCHUNK;
#pragma unroll
        for (int g = 0; g < 4; ++g) {
            sr[2*g]   = *(const float4*)(cp + g * 8);
            sr[2*g+1] = *(const float4*)(cp + g * 8 + 4);
        }
    };
    auto stage_write = [&](int b) {
#pragma unroll
        for (int g = 0; g < 4; ++g) {
            const float4 f0 = sr[2*g], f1 = sr[2*g+1];
            csq_part += f0.x*f0.x + f0.y*f0.y + f0.z*f0.z + f0.w*f0.w
                      + f1.x*f1.x + f1.y*f1.y + f1.z*f1.z + f1.w*f1.w;
            v8bf pk;
            pk[0]=(__bf16)f0.x; pk[1]=(__bf16)f0.y; pk[2]=(__bf16)f0.z; pk[3]=(__bf16)f0.w;
            pk[4]=(__bf16)f1.x; pk[5]=(__bf16)f1.y; pk[6]=(__bf16)f1.z; pk[7]=(__bf16)f1.w;
            const int dl = sd0 + g * 8;
            *(v8bf*)&Bs[b][scol * DCHUNK + (dl ^ ((scol & 7) << 3))] = pk;
        }
    };

    // ---- prologue: issue ALL A loads (16 outstanding), then C chunk 0 --------
    float4 ax[16];
#pragma unroll
    for (int c = 0; c < 4; ++c) {
        ax[4*c+0] = *(const float4*)(xrow + c*64);
        ax[4*c+1] = *(const float4*)(xrow + c*64 + 4);
        ax[4*c+2] = *(const float4*)(xrow + c*64 + 32);
        ax[4*c+3] = *(const float4*)(xrow + c*64 + 36);
    }
    stage_load(0);

    // convert A -> bf16 frags, exact fp32 xsq (frees the fp32 copies)
    float xsq = 0.f;
    v8bf af[8];
#pragma unroll
    for (int c = 0; c < 4; ++c) {
        const float4 a0 = ax[4*c], a1 = ax[4*c+1], a2 = ax[4*c+2], a3 = ax[4*c+3];
        xsq += a0.x*a0.x + a0.y*a0.y + a0.z*a0.z + a0.w*a0.w
             + a1.x*a1.x + a1.y*a1.y + a1.z*a1.z + a1.w*a1.w
             + a2.x*a2.x + a2.y*a2.y + a2.z*a2.z + a2.w*a2.w
             + a3.x*a3.x + a3.y*a3.y + a3.z*a3.z + a3.w*a3.w;
        v8bf f0, f1;
        f0[0]=(__bf16)a0.x; f0[1]=(__bf16)a0.y; f0[2]=(__bf16)a0.z; f0[3]=(__bf16)a0.w;
        f0[4]=(__bf16)a1.x; f0[5]=(__bf16)a1.y; f0[6]=(__bf16)a1.z; f0[7]=(__bf16)a1.w;
        f1[0]=(__bf16)a2.x; f1[1]=(__bf16)a2.y; f1[2]=(__bf16)a2.z; f1[3]=(__bf16)a2.w;
        f1[4]=(__bf16)a3.x; f1[5]=(__bf16)a3.y; f1[6]=(__bf16)a3.z; f1[7]=(__bf16)a3.w;
        af[2*c] = f0; af[2*c+1] = f1;
    }
    xsq += __shfl_xor(xsq, 16);
    xsq += __shfl_xor(xsq, 32);   // lanes with same lr now hold xsq(row lr)

    stage_write(0);               // waits on chunk-0 C loads only
    stage_load(1);                // in flight across the barrier + chunk-0 MFMA
    __syncthreads();              // buf0 ready

    f32x4 acc[16];
#pragma unroll
    for (int i = 0; i < 16; ++i) { acc[i][0]=0.f; acc[i][1]=0.f; acc[i][2]=0.f; acc[i][3]=0.f; }

    // ---- main loop: pure ds_read + MFMA; staging hidden behind it -----------
#pragma unroll
    for (int c = 0; c < 4; ++c) {
        const int b = c & 1;
#pragma unroll
        for (int tl = 0; tl < 16; ++tl) {
            const int col = tl * 16 + lr;
            const v8bf bf = *(const v8bf*)&Bs[b][col * DCHUNK + ((kg*8) ^ ((col & 7) << 3))];
            acc[tl] = __builtin_amdgcn_mfma_f32_16x16x32_bf16(af[2*c], bf, acc[tl], 0, 0, 0);
        }
#pragma unroll
        for (int tl = 0; tl < 16; ++tl) {
            const int col = tl * 16 + lr;
            const v8bf bf = *(const v8bf*)&Bs[b][col * DCHUNK + ((32 + kg*8) ^ ((col & 7) << 3))];
            acc[tl] = __builtin_amdgcn_mfma_f32_16x16x32_bf16(af[2*c+1], bf, acc[tl], 0, 0, 0);
        }
        if (c < 3) {
            __syncthreads();          // all waves done reading buf[b^1] (chunk c-1)
            stage_write(b ^ 1);       // sr was loaded one full chunk ago
            if (c < 2) stage_load(c + 2);
            __syncthreads();          // buf[b^1] ready
        }
    }

    // ---- c_sq finish (pair t,t^1 staged complementary halves of same col) ---
    csq_part += __shfl_xor(csq_part, 1);
    if ((t & 1) == 0) csq_s[scol] = csq_part;
    __syncthreads();                  // csq_s visible; also fences buf0 reuse

    float cs[16];
#pragma unroll
    for (int tl = 0; tl < 16; ++tl) cs[tl] = csq_s[tl * 16 + lr];

    // ---- epilogue: q + row-normalize + wave-private LDS transpose stores ----
    // acc C/D layout: col = lane&15 (=lr), row = kg*4 + j (m89-verified, R0-passed)
    float* tb = (float*)&Bs[0][0];    // 32KB = 8 waves x 4KB, wave-private
    const int twbase = wave * 1024;   // floats
#pragma unroll
    for (int j = 0; j < 4; ++j) {
        const float xs = __shfl(xsq, kg * 4 + j);
        float qv[16];
        float s = 0.f;
#pragma unroll
        for (int tl = 0; tl < 16; ++tl) {
            const float d2 = fmaxf(xs + cs[tl] - 2.f * acc[tl][j], 0.f);
            const float q = __builtin_amdgcn_rcpf(1.f + d2);
            qv[tl] = q;
            s += q;
        }
        s += __shfl_xor(s, 1);
        s += __shfl_xor(s, 2);
        s += __shfl_xor(s, 4);
        s += __shfl_xor(s, 8);
        const float r = __builtin_amdgcn_rcpf(s);
        // write (row kg, col tl*16+lr) -> tb[kg*256 + (col ^ kg*8)] (2-way max)
#pragma unroll
        for (int tl = 0; tl < 16; ++tl) {
            const int col = tl * 16 + lr;
            tb[twbase + kg * 256 + (col ^ (kg * 8))] = qv[tl] * r;
        }
        asm volatile("s_waitcnt lgkmcnt(0)" ::: "memory");  // wave-local transpose fence
#pragma unroll
        for (int i = 0; i < 4; ++i) {
            const f32x4 rv = *(const f32x4*)&tb[twbase + i * 256 + ((lane * 4) ^ (i * 8))];
            *(f32x4*)&out[(brow + wave * 16 + i * 4 + j) * DDIM + lane * 4] = rv;
        }
    }
}

extern "C" void kernel_launch(void* const* d_in, const int* in_sizes, int n_in,
                              void* d_out, int out_size, void* d_ws, size_t ws_size,
                              hipStream_t stream) {
    const float* X = (const float*)d_in[0];   // (N, 256) fp32
    const float* C = (const float*)d_in[1];   // (256, 256) fp32
    float* out = (float*)d_out;               // (N, 256) fp32
    const int N = in_sizes[0] / DDIM;
    const int nblocks = N / BM;               // 131072 -> 1024 blocks
    hipLaunchKernelGGL(cluster_soft_assign, dim3(nblocks), dim3(512), 0, stream,
                       X, C, out);
}

// Round 4
// 247.661 us; speedup vs baseline: 2.4228x; 1.0979x over previous
//
#include <hip/hip_runtime.h>
#include <hip/hip_bf16.h>

// ClusteringLayer: q[n,k] = norm_k( 1 / (1 + ||x_n - c_k||^2) ), alpha=1 (power=1 no-op)
// N=131072, D=256, K=256, fp32 in/out. HBM floor ~268MB -> ~43us.
// R3: fix the occupancy trap (R2 = 160 regs/wave -> 1 block/CU -> latency-bound).
//  - kernel1 pre-converts C -> bf16 in the pre-swizzled LDS image (+exact fp32 csq)
//  - kernel2: 256-thr blocks (4 waves, BM=64), single 32KB buffer staged via
//    global_load_lds DMA (zero staging regs) -> 33.25KB LDS -> 4 blocks/CU;
//    target <=128 regs -> 16 waves/CU of 4 INDEPENDENT blocks (phase diversity)
//  - keep R2's verified epilogue (rcp + wave-private LDS transpose, full-line stores)

#define DDIM 256
#define KCL  256
#define BM   64         // rows per block (4 waves x 16 rows)
#define DCHUNK 64

typedef __bf16 v8bf __attribute__((ext_vector_type(8)));
typedef __bf16 v4bf __attribute__((ext_vector_type(4)));
typedef float f32x4 __attribute__((ext_vector_type(4)));

// ---- kernel 1: C fp32 -> bf16 pre-swizzled chunk image + csq ---------------
// ws image: chunk c (64 d), element idx = c*16384 + col*64 + (d ^ ((col&7)<<3))
// -> kernel2's LDS staging is a LINEAR 32KB copy per chunk.
__global__ __launch_bounds__(256) void prep_clusters(
    const float* __restrict__ C, __bf16* __restrict__ wsB, float* __restrict__ wsCsq)
{
    const int t = threadIdx.x;
    const int wave = t >> 6, lane = t & 63;
    const int col = blockIdx.x * 4 + wave;            // 64 blocks x 4 waves = 256 cols
    const float4 v = *(const float4*)(C + (size_t)col * DDIM + lane * 4);
    float cs = v.x*v.x + v.y*v.y + v.z*v.z + v.w*v.w;
    cs += __shfl_xor(cs, 1);  cs += __shfl_xor(cs, 2);  cs += __shfl_xor(cs, 4);
    cs += __shfl_xor(cs, 8);  cs += __shfl_xor(cs, 16); cs += __shfl_xor(cs, 32);
    if (lane == 0) wsCsq[col] = cs;
    const int chunk = lane >> 4;                      // d/64 (lane*4 spans 0..255)
    const int dcb   = (lane * 4) & 63;                // d%64, multiple of 4
    const int sw    = (col & 7) << 3;                 // flips bits 3..5 only
    v4bf pk;
    pk[0] = (__bf16)v.x; pk[1] = (__bf16)v.y; pk[2] = (__bf16)v.z; pk[3] = (__bf16)v.w;
    *(v4bf*)&wsB[chunk * 16384 + col * DCHUNK + (dcb ^ sw)] = pk;   // 8B aligned
}

// ---- async global->LDS DMA (16B per lane, wave-uniform LDS base) -----------
__device__ __forceinline__ void gload_lds16(const void* g, void* l) {
    __builtin_amdgcn_global_load_lds(
        (const __attribute__((address_space(1))) unsigned int*)g,
        (__attribute__((address_space(3))) unsigned int*)l, 16, 0, 0);
}

// ---- kernel 2: fused distances + softmax-like normalize --------------------
__global__ __launch_bounds__(256, 4) void cluster_soft_assign(
    const float* __restrict__ X, const __bf16* __restrict__ wsB,
    const float* __restrict__ wsCsq, float* __restrict__ out)
{
    __shared__ __align__(16) __bf16 Bs[KCL * DCHUNK];   // 32 KB, single buffer
    __shared__ float csq_s[KCL];                        // 1 KB

    const int t    = threadIdx.x;
    const int wave = t >> 6;
    const int lane = t & 63;
    const int lr   = lane & 15;   // A row / C col fragment index
    const int kg   = lane >> 4;   // k-group

    const size_t brow = (size_t)blockIdx.x * BM;
    const float* xrow = X + (brow + wave * 16 + lr) * DDIM + kg * 8;

    csq_s[t] = wsCsq[t];

    // A chunk-0 prefetch (per chunk: d = c*64 + {0,32} + kg*8 + 0..7)
    float4 ax0 = *(const float4*)(xrow + 0);
    float4 ax1 = *(const float4*)(xrow + 4);
    float4 ax2 = *(const float4*)(xrow + 32);
    float4 ax3 = *(const float4*)(xrow + 36);

    f32x4 acc[16];
#pragma unroll
    for (int i = 0; i < 16; ++i) { acc[i][0]=0.f; acc[i][1]=0.f; acc[i][2]=0.f; acc[i][3]=0.f; }
    float xsq = 0.f;
    const int swl = (lr & 7) << 3;

    for (int c = 0; c < 4; ++c) {
        __syncthreads();   // c=0: csq_s visible; c>0: all waves done reading chunk c-1

        // DMA chunk c into Bs: 32 x 1KB segments, 8 per wave (linear copy of ws image)
        const __bf16* src = wsB + c * 16384;
#pragma unroll
        for (int i = 0; i < 8; ++i) {
            const int seg = wave * 8 + i;
            gload_lds16(src + seg * 512 + lane * 8, &Bs[seg * 512]);
        }

        // convert current A chunk -> bf16 frags; exact fp32 xsq (hides DMA latency)
        v8bf af0, af1;
        af0[0]=(__bf16)ax0.x; af0[1]=(__bf16)ax0.y; af0[2]=(__bf16)ax0.z; af0[3]=(__bf16)ax0.w;
        af0[4]=(__bf16)ax1.x; af0[5]=(__bf16)ax1.y; af0[6]=(__bf16)ax1.z; af0[7]=(__bf16)ax1.w;
        af1[0]=(__bf16)ax2.x; af1[1]=(__bf16)ax2.y; af1[2]=(__bf16)ax2.z; af1[3]=(__bf16)ax2.w;
        af1[4]=(__bf16)ax3.x; af1[5]=(__bf16)ax3.y; af1[6]=(__bf16)ax3.z; af1[7]=(__bf16)ax3.w;
        xsq += ax0.x*ax0.x + ax0.y*ax0.y + ax0.z*ax0.z + ax0.w*ax0.w
             + ax1.x*ax1.x + ax1.y*ax1.y + ax1.z*ax1.z + ax1.w*ax1.w
             + ax2.x*ax2.x + ax2.y*ax2.y + ax2.z*ax2.z + ax2.w*ax2.w
             + ax3.x*ax3.x + ax3.y*ax3.y + ax3.z*ax3.z + ax3.w*ax3.w;

        __syncthreads();   // drains DMA (vmcnt) + barrier: Bs ready

        // issue next chunk's A loads now -> in flight across the MFMA phase
        if (c < 3) {
            const float* xp = xrow + (c + 1) * 64;
            ax0 = *(const float4*)(xp);
            ax1 = *(const float4*)(xp + 4);
            ax2 = *(const float4*)(xp + 32);
            ax3 = *(const float4*)(xp + 36);
        }

#pragma unroll
        for (int tl = 0; tl < 16; ++tl) {
            const int col = tl * 16 + lr;
            const v8bf b0 = *(const v8bf*)&Bs[col * DCHUNK + ((kg * 8) ^ swl)];
            acc[tl] = __builtin_amdgcn_mfma_f32_16x16x32_bf16(af0, b0, acc[tl], 0, 0, 0);
        }
#pragma unroll
        for (int tl = 0; tl < 16; ++tl) {
            const int col = tl * 16 + lr;
            const v8bf b1 = *(const v8bf*)&Bs[col * DCHUNK + ((32 + kg * 8) ^ swl)];
            acc[tl] = __builtin_amdgcn_mfma_f32_16x16x32_bf16(af1, b1, acc[tl], 0, 0, 0);
        }
    }

    // xsq: reduce over the 4 k-groups -> lane holds xsq(row = lane&15)
    xsq += __shfl_xor(xsq, 16);
    xsq += __shfl_xor(xsq, 32);

    float cs_[16];
#pragma unroll
    for (int tl = 0; tl < 16; ++tl) cs_[tl] = csq_s[tl * 16 + lr];

    __syncthreads();   // all waves done with chunk-3 Bs reads -> Bs reusable as scratch

    // epilogue: acc C/D layout col = lane&15, row = kg*4 + j (R0/R2-verified)
    float* tb = (float*)&Bs[0] + wave * 1024;   // wave-private 4 KB
#pragma unroll
    for (int j = 0; j < 4; ++j) {
        const float xs = __shfl(xsq, kg * 4 + j);
        float qv[16];
        float s = 0.f;
#pragma unroll
        for (int tl = 0; tl < 16; ++tl) {
            const float d2 = fmaxf(xs + cs_[tl] - 2.f * acc[tl][j], 0.f);
            const float q = __builtin_amdgcn_rcpf(1.f + d2);
            qv[tl] = q;
            s += q;
        }
        s += __shfl_xor(s, 1);
        s += __shfl_xor(s, 2);
        s += __shfl_xor(s, 4);
        s += __shfl_xor(s, 8);
        const float r = __builtin_amdgcn_rcpf(s);
#pragma unroll
        for (int tl = 0; tl < 16; ++tl) {
            const int col = tl * 16 + lr;
            tb[kg * 256 + (col ^ (kg * 8))] = qv[tl] * r;
        }
        asm volatile("s_waitcnt lgkmcnt(0)" ::: "memory");  // wave-local transpose fence
#pragma unroll
        for (int i = 0; i < 4; ++i) {
            const f32x4 rv = *(const f32x4*)&tb[i * 256 + ((lane * 4) ^ (i * 8))];
            *(f32x4*)&out[(brow + wave * 16 + i * 4 + j) * DDIM + lane * 4] = rv;
        }
    }
}

extern "C" void kernel_launch(void* const* d_in, const int* in_sizes, int n_in,
                              void* d_out, int out_size, void* d_ws, size_t ws_size,
                              hipStream_t stream) {
    const float* X = (const float*)d_in[0];   // (N, 256) fp32
    const float* C = (const float*)d_in[1];   // (256, 256) fp32
    float* out = (float*)d_out;               // (N, 256) fp32
    __bf16* wsB   = (__bf16*)d_ws;                          // 128 KB
    float*  wsCsq = (float*)((char*)d_ws + KCL * DDIM * 2); // +1 KB
    const int N = in_sizes[0] / DDIM;
    const int nblocks = N / BM;               // 131072 -> 2048 blocks

    hipLaunchKernelGGL(prep_clusters, dim3(KCL / 4), dim3(256), 0, stream, C, wsB, wsCsq);
    hipLaunchKernelGGL(cluster_soft_assign, dim3(nblocks), dim3(256), 0, stream,
                       X, wsB, wsCsq, out);
}